// Round 1
// baseline (83510.132 us; speedup 1.0000x reference)
//
#include <hip/hip_runtime.h>
#include <math.h>

#define DEV __device__ __forceinline__

constexpr int Bn = 4, En = 768, Hn = 3072, Tt = 256, Vn = 50257;

DEV float wred(float v) {
#pragma unroll
  for (int o = 32; o > 0; o >>= 1) v += __shfl_down(v, o, 64);
  return v;
}

DEV float gelu_exact(float x) { return 0.5f * x * (1.0f + erff(x * 0.70710678118654752440f)); }

// ---------------- embedding gather + L2-normalize (all t,b up front) ----------------
__global__ __launch_bounds__(256) void k_emb_norm(const int* __restrict__ ids,
                                                  const float* __restrict__ emb,
                                                  float* __restrict__ emb_all) {
  int r = blockIdx.x;  // r = t*Bn + b
  int t = r >> 2, b = r & 3;
  int tok = ids[b * Tt + t];
  const float* src = emb + (size_t)tok * En;
  float ss = 0.f;
  for (int e = threadIdx.x; e < En; e += 256) { float v = src[e]; ss += v * v; }
  __shared__ float red[4];
  float w = wred(ss);
  if ((threadIdx.x & 63) == 0) red[threadIdx.x >> 6] = w;
  __syncthreads();
  float tot = red[0] + red[1] + red[2] + red[3];
  float rn = 1.f / fmaxf(sqrtf(tot), 1e-12f);
  float* dst = emb_all + (size_t)r * En;
  for (int e = threadIdx.x; e < En; e += 256) dst[e] = src[e] * rn;
}

// ---------------- layernorm of h (4 rows, one wave per row) ----------------
DEV void ln4(const float* __restrict__ h, const float* __restrict__ g,
             const float* __restrict__ bb, float* __restrict__ dst) {
  int b = threadIdx.x >> 6, lane = threadIdx.x & 63;
  const float* row = h + b * En;
  float s = 0.f;
  for (int e = lane; e < En; e += 64) s += row[e];
  s = wred(s); s = __shfl(s, 0, 64);
  float m = s / (float)En;
  float v = 0.f;
  for (int e = lane; e < En; e += 64) { float d = row[e] - m; v += d * d; }
  v = wred(v); v = __shfl(v, 0, 64);
  float inv = 1.f / sqrtf(v / (float)En + 1e-5f);
  float* o = dst + b * En;
  for (int e = lane; e < En; e += 64) o[e] = (row[e] - m) * inv * g[e] + bb[e];
}

__global__ __launch_bounds__(256) void k_lnfin(const float* __restrict__ h, const float* __restrict__ g,
                                               const float* __restrict__ b, float* __restrict__ dst) {
  ln4(h, g, b, dst);
}

// ---------------- step stage 0: temporal_raw = h@R, ctx = emb + a*tr; block 12: LN(prev h) ----------------
__global__ __launch_bounds__(256) void k_step0(const float* __restrict__ Rw, const float* __restrict__ h,
                                               const float* __restrict__ emb_all,
                                               float* __restrict__ tr, float* __restrict__ ctx,
                                               float* __restrict__ fused,
                                               const float* __restrict__ ln_g, const float* __restrict__ ln_b,
                                               int t) {
  int blk = blockIdx.x, tid = threadIdx.x;
  if (blk < 12) {
    __shared__ float hl[Bn * En];
    __shared__ float red[4][64][Bn];
    for (int i = tid; i < Bn * En; i += 256) hl[i] = h[i];
    __syncthreads();
    int c = tid & 63, ks = tid >> 6;
    int n = blk * 64 + c;
    float a0 = 0, a1 = 0, a2 = 0, a3 = 0;
    for (int k = ks * 192, ke = k + 192; k < ke; ++k) {
      float w = Rw[(size_t)k * En + n];
      a0 += hl[0 * En + k] * w; a1 += hl[1 * En + k] * w;
      a2 += hl[2 * En + k] * w; a3 += hl[3 * En + k] * w;
    }
    red[ks][c][0] = a0; red[ks][c][1] = a1; red[ks][c][2] = a2; red[ks][c][3] = a3;
    __syncthreads();
    if (ks == 0) {
      const float* et = emb_all + (size_t)t * Bn * En;
#pragma unroll
      for (int b = 0; b < Bn; ++b) {
        float s = red[0][c][b] + red[1][c][b] + red[2][c][b] + red[3][c][b];
        tr[b * En + n] = s;
        ctx[b * En + n] = et[b * En + n] + 0.4f * s;
      }
    }
  } else if (t > 0) {
    ln4(h, ln_g, ln_b, fused + (size_t)(t - 1) * Bn * En);
  }
}

// ---------------- PC iteration phase A: e0 = ctx - tanh(x1)@W1 ; e1 = x1 - tanh(x2)@W2 ----------------
// blocks 0..11 -> e0 (N=En), 12..59 -> e1 (N=Hn), block 60 (final launch only) -> rnorm of x2
__global__ __launch_bounds__(256) void k_iterA(const float* __restrict__ W1, const float* __restrict__ W2,
                                               const float* __restrict__ x1, const float* __restrict__ x2,
                                               const float* __restrict__ ctx,
                                               float* __restrict__ e0, float* __restrict__ e1,
                                               float* __restrict__ rnorm) {
  __shared__ float smem[Bn * Hn];
  __shared__ float red[4][64][Bn];
  int blk = blockIdx.x, tid = threadIdx.x;
  if (blk < 12) {
    for (int i = tid; i < Bn * Hn; i += 256) smem[i] = tanhf(x1[i]);
    __syncthreads();
    int c = tid & 63, ks = tid >> 6;
    int n = blk * 64 + c;
    float a0 = 0, a1 = 0, a2 = 0, a3 = 0;
    for (int k = ks * 768, ke = k + 768; k < ke; ++k) {
      float w = W1[(size_t)k * En + n];
      a0 += smem[0 * Hn + k] * w; a1 += smem[1 * Hn + k] * w;
      a2 += smem[2 * Hn + k] * w; a3 += smem[3 * Hn + k] * w;
    }
    red[ks][c][0] = a0; red[ks][c][1] = a1; red[ks][c][2] = a2; red[ks][c][3] = a3;
    __syncthreads();
    if (ks == 0) {
#pragma unroll
      for (int b = 0; b < Bn; ++b) {
        float s = red[0][c][b] + red[1][c][b] + red[2][c][b] + red[3][c][b];
        e0[b * En + n] = ctx[b * En + n] - s;
      }
    }
  } else if (blk < 60) {
    for (int i = tid; i < Bn * En; i += 256) smem[i] = tanhf(x2[i]);
    __syncthreads();
    int c = tid & 63, ks = tid >> 6;
    int n = (blk - 12) * 64 + c;
    float a0 = 0, a1 = 0, a2 = 0, a3 = 0;
    for (int k = ks * 192, ke = k + 192; k < ke; ++k) {
      float w = W2[(size_t)k * Hn + n];
      a0 += smem[0 * En + k] * w; a1 += smem[1 * En + k] * w;
      a2 += smem[2 * En + k] * w; a3 += smem[3 * En + k] * w;
    }
    red[ks][c][0] = a0; red[ks][c][1] = a1; red[ks][c][2] = a2; red[ks][c][3] = a3;
    __syncthreads();
    if (ks == 0) {
#pragma unroll
      for (int b = 0; b < Bn; ++b) {
        float s = red[0][c][b] + red[1][c][b] + red[2][c][b] + red[3][c][b];
        e1[b * Hn + n] = x1[b * Hn + n] - s;
      }
    }
  } else {
    int b = tid >> 6, lane = tid & 63;
    float ss = 0.f;
    for (int e = lane; e < En; e += 64) { float v = x2[b * En + e]; ss += v * v; }
    ss = wred(ss);
    if (lane == 0) rnorm[b] = 1.f / fmaxf(sqrtf(ss), 1e-12f);
  }
}

// ---------------- generic "A @ W^T" 16-col x 16-ksplit block helper ----------------
template <int K>
DEV void tn16(const float* __restrict__ W, const float* __restrict__ srcLds,
              float (*red)[16][Bn], int n, float out[Bn]) {
  int tid = threadIdx.x;
  int c = tid & 15, ks = tid >> 4;
  constexpr int CH = K / 16;
  float a0 = 0, a1 = 0, a2 = 0, a3 = 0;
  const float4* wr = (const float4*)(W + (size_t)n * K + ks * CH);
#pragma unroll 4
  for (int q = 0; q < CH / 4; ++q) {
    float4 w = wr[q];
    int k = ks * CH + q * 4;
    const float* s0 = srcLds + 0 * K + k;
    const float* s1 = srcLds + 1 * K + k;
    const float* s2 = srcLds + 2 * K + k;
    const float* s3 = srcLds + 3 * K + k;
    a0 += s0[0] * w.x + s0[1] * w.y + s0[2] * w.z + s0[3] * w.w;
    a1 += s1[0] * w.x + s1[1] * w.y + s1[2] * w.z + s1[3] * w.w;
    a2 += s2[0] * w.x + s2[1] * w.y + s2[2] * w.z + s2[3] * w.w;
    a3 += s3[0] * w.x + s3[1] * w.y + s3[2] * w.z + s3[3] * w.w;
  }
  red[ks][c][0] = a0; red[ks][c][1] = a1; red[ks][c][2] = a2; red[ks][c][3] = a3;
  __syncthreads();
  if (ks == 0) {
#pragma unroll
    for (int b = 0; b < Bn; ++b) {
      float s = 0.f;
#pragma unroll
      for (int q = 0; q < 16; ++q) s += red[q][c][b];
      out[b] = s;
    }
  }
}

// ---------------- PC iteration phase B: x1 += .1((e0@W1^T)(1-f1^2)-e1); x2 += .1((e1@W2^T)(1-f2^2)) ----------------
__global__ __launch_bounds__(256) void k_iterB(const float* __restrict__ W1, const float* __restrict__ W2,
                                               float* __restrict__ x1, float* __restrict__ x2,
                                               const float* __restrict__ e0, const float* __restrict__ e1) {
  __shared__ float smem[Bn * Hn];
  __shared__ float red[16][16][Bn];
  int blk = blockIdx.x, tid = threadIdx.x;
  int c = tid & 15, ks = tid >> 4;
  float s[Bn];
  if (blk < 192) {
    for (int i = tid; i < Bn * En; i += 256) smem[i] = e0[i];
    __syncthreads();
    int n = blk * 16 + c;
    tn16<En>(W1, smem, red, n, s);
    if (ks == 0) {
#pragma unroll
      for (int b = 0; b < Bn; ++b) {
        float xo = x1[b * Hn + n];
        float f = tanhf(xo);
        x1[b * Hn + n] = xo + 0.1f * (s[b] * (1.f - f * f) - e1[b * Hn + n]);
      }
    }
  } else {
    for (int i = tid; i < Bn * Hn; i += 256) smem[i] = e1[i];
    __syncthreads();
    int n = (blk - 192) * 16 + c;
    tn16<Hn>(W2, smem, red, n, s);
    if (ks == 0) {
#pragma unroll
      for (int b = 0; b < Bn; ++b) {
        float xo = x2[b * En + n];
        float f = tanhf(xo);
        x2[b * En + n] = xo + 0.1f * s[b] * (1.f - f * f);
      }
    }
  }
}

// ---------------- cf1 = gelu(core_raw@Wc1^T + bc1); tf = tr@Wt^T ----------------
__global__ __launch_bounds__(256) void k_tn2(const float* __restrict__ Wc1, const float* __restrict__ bc1,
                                             const float* __restrict__ Wt,
                                             const float* __restrict__ x2, const float* __restrict__ rnorm,
                                             const float* __restrict__ tr,
                                             float* __restrict__ cf1, float* __restrict__ tf) {
  __shared__ float smem[Bn * En];
  __shared__ float red[16][16][Bn];
  int blk = blockIdx.x, tid = threadIdx.x;
  int c = tid & 15, ks = tid >> 4;
  float s[Bn];
  if (blk < 48) {
    for (int i = tid; i < Bn * En; i += 256) smem[i] = x2[i] * rnorm[i / En];
    __syncthreads();
    int n = blk * 16 + c;
    tn16<En>(Wc1, smem, red, n, s);
    if (ks == 0)
      for (int b = 0; b < Bn; ++b) cf1[b * En + n] = gelu_exact(s[b] + bc1[n]);
  } else {
    for (int i = tid; i < Bn * En; i += 256) smem[i] = tr[i];
    __syncthreads();
    int n = (blk - 48) * 16 + c;
    tn16<En>(Wt, smem, red, n, s);
    if (ks == 0)
      for (int b = 0; b < Bn; ++b) tf[b * En + n] = s[b];
  }
}

// ---------------- R update: R = clip(.999R + (eta_r/B) * h^T (core_raw - tr)) ----------------
__global__ __launch_bounds__(256) void k_R(float* __restrict__ Rw, const float* __restrict__ h,
                                           const float* __restrict__ x2, const float* __restrict__ rnorm,
                                           const float* __restrict__ tr) {
  int idx = (blockIdx.x * 256 + threadIdx.x) * 4;
  int i = idx / En, j = idx % En;
  float4 r = *(const float4*)(Rw + idx);
  float d0 = 0, d1 = 0, d2 = 0, d3 = 0;
#pragma unroll
  for (int b = 0; b < Bn; ++b) {
    float hv = h[b * En + i];
    float rb = rnorm[b];
    const float* x2r = x2 + b * En + j;
    const float* trr = tr + b * En + j;
    d0 += hv * (x2r[0] * rb - trr[0]);
    d1 += hv * (x2r[1] * rb - trr[1]);
    d2 += hv * (x2r[2] * rb - trr[2]);
    d3 += hv * (x2r[3] * rb - trr[3]);
  }
  const float cc = 0.005f * 0.25f;
  r.x = fminf(fmaxf(0.999f * r.x + cc * d0, -3.f), 3.f);
  r.y = fminf(fmaxf(0.999f * r.y + cc * d1, -3.f), 3.f);
  r.z = fminf(fmaxf(0.999f * r.z + cc * d2, -3.f), 3.f);
  r.w = fminf(fmaxf(0.999f * r.w + cc * d3, -3.f), 3.f);
  *(float4*)(Rw + idx) = r;
}

// ---------------- W1/W2 Hebbian update + cf2 = cf1@Wc2^T + bc2 ----------------
__global__ __launch_bounds__(256) void k_Wcf(const float* __restrict__ Wc2, const float* __restrict__ bc2,
                                             const float* __restrict__ cf1, float* __restrict__ cf2,
                                             float* __restrict__ W1, float* __restrict__ W2,
                                             const float* __restrict__ x1, const float* __restrict__ x2,
                                             const float* __restrict__ e0, const float* __restrict__ e1) {
  __shared__ float smem[Bn * En];
  __shared__ float red[16][16][Bn];
  int blk = blockIdx.x, tid = threadIdx.x;
  if (blk < 48) {
    int c = tid & 15, ks = tid >> 4;
    for (int i = tid; i < Bn * En; i += 256) smem[i] = cf1[i];
    __syncthreads();
    int n = blk * 16 + c;
    float s[Bn];
    tn16<En>(Wc2, smem, red, n, s);
    if (ks == 0)
      for (int b = 0; b < Bn; ++b) cf2[b * En + n] = s[b] + bc2[n];
  } else if (blk < 48 + 2304) {
    int idx = (blk - 48) * 1024 + tid * 4;
    int k = idx / En, n = idx % En;
    float4 w = *(const float4*)(W1 + idx);
    float f[Bn];
#pragma unroll
    for (int b = 0; b < Bn; ++b) f[b] = tanhf(x1[b * Hn + k]);
#pragma unroll
    for (int b = 0; b < Bn; ++b) {
      const float* er = e0 + b * En + n;
      w.x += 0.0025f * f[b] * er[0];
      w.y += 0.0025f * f[b] * er[1];
      w.z += 0.0025f * f[b] * er[2];
      w.w += 0.0025f * f[b] * er[3];
    }
    *(float4*)(W1 + idx) = w;
  } else {
    int idx = (blk - 48 - 2304) * 1024 + tid * 4;
    int k = idx / Hn, n = idx % Hn;
    float4 w = *(const float4*)(W2 + idx);
    float f[Bn];
#pragma unroll
    for (int b = 0; b < Bn; ++b) f[b] = tanhf(x2[b * En + k]);
#pragma unroll
    for (int b = 0; b < Bn; ++b) {
      const float* er = e1 + b * Hn + n;
      w.x += 0.0025f * f[b] * er[0];
      w.y += 0.0025f * f[b] * er[1];
      w.z += 0.0025f * f[b] * er[2];
      w.w += 0.0025f * f[b] * er[3];
    }
    *(float4*)(W2 + idx) = w;
  }
}

// ---------------- gate + h_t ----------------
__global__ __launch_bounds__(256) void k_gate(const float* __restrict__ Wg, const float* __restrict__ bg,
                                              const float* __restrict__ emb_all, const float* __restrict__ cf2,
                                              const float* __restrict__ tf, float* __restrict__ h, int t) {
  __shared__ float smem[Bn * 2 * En];
  __shared__ float red[16][16][Bn];
  int tid = threadIdx.x;
  const float* et = emb_all + (size_t)t * Bn * En;
  for (int i = tid; i < Bn * 2 * En; i += 256) {
    int b = i / (2 * En), k = i % (2 * En);
    smem[i] = (k < En) ? et[b * En + k] : cf2[b * En + (k - En)];
  }
  __syncthreads();
  int c = tid & 15, ks = tid >> 4;
  int n = blockIdx.x * 16 + c;
  float s[Bn];
  tn16<2 * En>(Wg, smem, red, n, s);
  if (ks == 0) {
#pragma unroll
    for (int b = 0; b < Bn; ++b) {
      float g = 1.f / (1.f + expf(-(s[b] + bg[n])));
      float e = et[b * En + n];
      h[b * En + n] = g * (cf2[b * En + n] + 0.4f * tf[b * En + n]) + (1.f - g) * e;
    }
  }
}

// ---------------- final logits GEMM: out[b,t,v] = fused[t*Bn+b,:] . embedding[v,:] ----------------
__global__ __launch_bounds__(256) void k_gemm(const float* __restrict__ F, const float* __restrict__ emb,
                                              float* __restrict__ out) {
  __shared__ float As[64][17];
  __shared__ float Bs[64][17];
  int vb = blockIdx.x * 64;
  int mb = blockIdx.y * 64;
  int tid = threadIdx.x;
  int tx = tid & 15, ty = tid >> 4;
  float acc[4][4] = {{0}};
  int ar = tid >> 2, kq = (tid & 3) * 4;
  for (int k0 = 0; k0 < En; k0 += 16) {
    float4 a4 = *(const float4*)&F[(size_t)(mb + ar) * En + k0 + kq];
    As[ar][kq + 0] = a4.x; As[ar][kq + 1] = a4.y; As[ar][kq + 2] = a4.z; As[ar][kq + 3] = a4.w;
    int br = vb + ar;
    float4 b4 = make_float4(0.f, 0.f, 0.f, 0.f);
    if (br < Vn) b4 = *(const float4*)&emb[(size_t)br * En + k0 + kq];
    Bs[ar][kq + 0] = b4.x; Bs[ar][kq + 1] = b4.y; Bs[ar][kq + 2] = b4.z; Bs[ar][kq + 3] = b4.w;
    __syncthreads();
#pragma unroll
    for (int k = 0; k < 16; ++k) {
      float av[4], bv[4];
#pragma unroll
      for (int i = 0; i < 4; ++i) av[i] = As[ty * 4 + i][k];
#pragma unroll
      for (int j = 0; j < 4; ++j) bv[j] = Bs[tx * 4 + j][k];
#pragma unroll
      for (int i = 0; i < 4; ++i)
#pragma unroll
        for (int j = 0; j < 4; ++j) acc[i][j] += av[i] * bv[j];
    }
    __syncthreads();
  }
#pragma unroll
  for (int i = 0; i < 4; ++i) {
    int m = mb + ty * 4 + i;
    int b = m & 3, t = m >> 2;
    float* orow = out + ((size_t)b * Tt + t) * Vn;
#pragma unroll
    for (int j = 0; j < 4; ++j) {
      int v = vb + tx * 4 + j;
      if (v < Vn) orow[v] = acc[i][j];
    }
  }
}

extern "C" void kernel_launch(void* const* d_in, const int* in_sizes, int n_in,
                              void* d_out, int out_size, void* d_ws, size_t ws_size,
                              hipStream_t stream) {
  const int* token_ids = (const int*)d_in[0];
  const float* embedding = (const float*)d_in[1];
  const float* Wc1 = (const float*)d_in[2];
  const float* bc1 = (const float*)d_in[3];
  const float* Wc2 = (const float*)d_in[4];
  const float* bc2 = (const float*)d_in[5];
  const float* Wg = (const float*)d_in[6];
  const float* bg = (const float*)d_in[7];
  const float* Wt = (const float*)d_in[8];
  const float* R0 = (const float*)d_in[9];
  const float* ln_g = (const float*)d_in[10];
  const float* ln_b = (const float*)d_in[11];
  const float* W1_0 = (const float*)d_in[12];
  const float* W2_0 = (const float*)d_in[13];
  const float* x1_0 = (const float*)d_in[14];
  const float* x2_0 = (const float*)d_in[15];
  (void)in_sizes; (void)n_in; (void)out_size; (void)ws_size;

  float* ws = (float*)d_ws;
  size_t off = 0;
  float* R = ws + off;        off += (size_t)En * En;       // 589824
  float* W1 = ws + off;       off += (size_t)Hn * En;       // 2359296
  float* W2 = ws + off;       off += (size_t)En * Hn;       // 2359296
  float* x1 = ws + off;       off += Bn * Hn;
  float* x2 = ws + off;       off += Bn * En;
  float* h = ws + off;        off += Bn * En;
  float* emb_all = ws + off;  off += (size_t)Tt * Bn * En;  // 786432
  float* fused = ws + off;    off += (size_t)Tt * Bn * En;  // 786432
  float* tr = ws + off;       off += Bn * En;
  float* ctx = ws + off;      off += Bn * En;
  float* e0 = ws + off;       off += Bn * En;
  float* e1 = ws + off;       off += Bn * Hn;
  float* rnorm = ws + off;    off += 64;
  float* cf1 = ws + off;      off += Bn * En;
  float* cf2 = ws + off;      off += Bn * En;
  float* tf = ws + off;       off += Bn * En;

  // mutable state initialized from pristine inputs every launch
  hipMemcpyAsync(R, R0, (size_t)En * En * 4, hipMemcpyDeviceToDevice, stream);
  hipMemcpyAsync(W1, W1_0, (size_t)Hn * En * 4, hipMemcpyDeviceToDevice, stream);
  hipMemcpyAsync(W2, W2_0, (size_t)En * Hn * 4, hipMemcpyDeviceToDevice, stream);
  hipMemcpyAsync(x1, x1_0, (size_t)Bn * Hn * 4, hipMemcpyDeviceToDevice, stream);
  hipMemcpyAsync(x2, x2_0, (size_t)Bn * En * 4, hipMemcpyDeviceToDevice, stream);
  hipMemsetAsync(h, 0, (size_t)Bn * En * 4, stream);

  k_emb_norm<<<Tt * Bn, 256, 0, stream>>>(token_ids, embedding, emb_all);

  for (int t = 0; t < Tt; ++t) {
    k_step0<<<13, 256, 0, stream>>>(R, h, emb_all, tr, ctx, fused, ln_g, ln_b, t);
    for (int it = 0; it < 3; ++it) {
      k_iterA<<<60, 256, 0, stream>>>(W1, W2, x1, x2, ctx, e0, e1, rnorm);
      k_iterB<<<240, 256, 0, stream>>>(W1, W2, x1, x2, e0, e1);
    }
    k_iterA<<<61, 256, 0, stream>>>(W1, W2, x1, x2, ctx, e0, e1, rnorm);  // final + rnorm
    k_tn2<<<96, 256, 0, stream>>>(Wc1, bc1, Wt, x2, rnorm, tr, cf1, tf);
    k_R<<<576, 256, 0, stream>>>(R, h, x2, rnorm, tr);
    k_Wcf<<<48 + 2304 + 2304, 256, 0, stream>>>(Wc2, bc2, cf1, cf2, W1, W2, x1, x2, e0, e1);
    k_gate<<<48, 256, 0, stream>>>(Wg, bg, emb_all, cf2, tf, h, t);
  }
  k_lnfin<<<1, 256, 0, stream>>>(h, ln_g, ln_b, fused + (size_t)(Tt - 1) * Bn * En);

  dim3 gg((Vn + 63) / 64, (Bn * Tt) / 64);
  k_gemm<<<gg, 256, 0, stream>>>(fused, embedding, (float*)d_out);
}